// Round 16
// baseline (189.652 us; speedup 1.0000x reference)
//
#include <hip/hip_runtime.h>
#include <stdint.h>

#define Nn 50000
#define Ee 800000
#define FIN 128
#define HIDD 256
#define CLSS 64

#define NBIN 98          // ceil(50000 / 512)
#define BSH 9
#define BINSZ 512
#define BCAP 16384
#define EPB 2048
#define NEB ((Ee + EPB - 1) / EPB)   // 391

#define MT32 1563        // ceil(50000/32)
#define GXF 256          // M-group blocks per job for fused GEMM (512 blocks total)

#define SHP 264          // padded sH row stride (us_t)

typedef unsigned int uint_t;
typedef unsigned short us_t;
typedef __attribute__((ext_vector_type(8))) short short8;
typedef __attribute__((ext_vector_type(4))) float f32x4;
typedef __attribute__((ext_vector_type(2))) float f32x2;

__device__ inline float bflo(uint_t v) { union { uint_t u; float f; } c; c.u = v << 16; return c.f; }
__device__ inline float bfhi(uint_t v) { union { uint_t u; float f; } c; c.u = v & 0xffff0000u; return c.f; }
__device__ inline us_t f2bf(float f) {
    union { float f; uint_t u; } c; c.f = f;
    uint_t u = c.u;
    u += 0x7fffu + ((u >> 16) & 1u);
    return (us_t)(u >> 16);
}

#define GLOAD(gp, lp)                                                      \
    __builtin_amdgcn_global_load_lds(                                      \
        (const __attribute__((address_space(1))) unsigned int*)(gp),       \
        (__attribute__((address_space(3))) unsigned int*)(lp), 16, 0, 0)

// ================= merged front-end: k_bin || cvtw || cvtx =================
__global__ __launch_bounds__(512) void k_front(
    const int* __restrict__ ei,
    const float* __restrict__ xu, const float* __restrict__ xp,
    const float* __restrict__ w1, const float* __restrict__ w2,
    const float* __restrict__ w3, const float* __restrict__ w4,
    const float* __restrict__ w5, const float* __restrict__ w6,
    const float* __restrict__ w7, const float* __restrict__ w8,
    us_t* __restrict__ cu, us_t* __restrict__ cp,
    uint_t* __restrict__ f8u, uint_t* __restrict__ f8p,
    us_t* __restrict__ wc10, us_t* __restrict__ wc11,
    us_t* __restrict__ wc20, us_t* __restrict__ wc21,
    int* __restrict__ bin_cnt,
    uint_t* __restrict__ ent_p, uint_t* __restrict__ ent_u) {
    __shared__ int hist[2 * NBIN];
    __shared__ int base[2 * NBIN];
    int bx = blockIdx.x, tid = threadIdx.x;

    if (bx < NEB) {
        int e0 = bx * EPB;
        int n = Ee - e0; if (n > EPB) n = EPB;
        for (int i = tid; i < 2 * NBIN; i += 512) hist[i] = 0;
        __syncthreads();
        for (int i = tid; i < n; i += 512) {
            int u = ei[e0 + i], p = ei[Ee + e0 + i];
            atomicAdd(&hist[p >> BSH], 1);
            atomicAdd(&hist[NBIN + (u >> BSH)], 1);
        }
        __syncthreads();
        for (int i = tid; i < 2 * NBIN; i += 512) {
            int c = hist[i];
            base[i] = c ? atomicAdd(&bin_cnt[i], c) : 0;
        }
        __syncthreads();
        for (int i = tid; i < 2 * NBIN; i += 512) hist[i] = base[i];
        __syncthreads();
        for (int i = tid; i < n; i += 512) {
            int u = ei[e0 + i], p = ei[Ee + e0 + i];
            int bp = p >> BSH, bu = u >> BSH;
            int rp = atomicAdd(&hist[bp], 1);
            if (rp < BCAP)
                ent_p[(size_t)bp * BCAP + rp] = ((uint_t)(p & (BINSZ - 1)) << 16) | (uint_t)u;
            int ru = atomicAdd(&hist[NBIN + bu], 1);
            if (ru < BCAP)
                ent_u[(size_t)bu * BCAP + ru] = ((uint_t)(u & (BINSZ - 1)) << 16) | (uint_t)p;
        }
    } else if (bx < NEB + 96) {
        int i = (bx - NEB) * 512 + tid;
        const float* wp; us_t* dst;
        if (i < 32768) {
            int seg = i >> 13; int loc = i & 8191;
            int row = loc >> 5, col = (loc & 31) * 4;
            switch (seg) {
                case 0: wp = w1; dst = wc10 + (size_t)row * 256 + col; break;
                case 1: wp = w2; dst = wc10 + (size_t)row * 256 + 128 + col; break;
                case 2: wp = w3; dst = wc11 + (size_t)row * 256 + col; break;
                default: wp = w4; dst = wc11 + (size_t)row * 256 + 128 + col; break;
            }
            float4 v = reinterpret_cast<const float4*>(wp)[i & 8191];
            ushort4 o;
            o.x = f2bf(v.x); o.y = f2bf(v.y); o.z = f2bf(v.z); o.w = f2bf(v.w);
            *reinterpret_cast<ushort4*>(dst) = o;
        } else {
            int j = i - 32768;
            int seg = j >> 12; int loc = j & 4095;
            switch (seg) {
                case 0: wp = w5; dst = wc20; break;
                case 1: wp = w6; dst = wc21 + 64 * 256; break;
                case 2: wp = w7; dst = wc21; break;
                default: wp = w8; dst = wc20 + 64 * 256; break;
            }
            float4 v = reinterpret_cast<const float4*>(wp)[loc];
            ushort4 o;
            o.x = f2bf(v.x); o.y = f2bf(v.y); o.z = f2bf(v.z); o.w = f2bf(v.w);
            reinterpret_cast<ushort4*>(dst)[loc] = o;
        }
    } else {
        int bcx = bx - NEB - 96;
        int side = bcx & 1;
        const float* in = side ? xp : xu;
        us_t* comb = side ? cu : cp;
        uint_t* o8 = side ? f8p : f8u;
        const int n4 = (Nn * FIN) / 4;
        int i = (bcx >> 1) * 512 + tid;
        int stride = 256 * 512;
        for (; i < n4; i += stride) {
            float4 v = reinterpret_cast<const float4*>(in)[i];
            ushort4 o;
            o.x = f2bf(v.x); o.y = f2bf(v.y); o.z = f2bf(v.z); o.w = f2bf(v.w);
            int node = i >> 5;
            int col = (i & 31) * 4;
            *reinterpret_cast<ushort4*>(comb + (size_t)node * 256 + 128 + col) = o;
            int pk = __builtin_amdgcn_cvt_pk_fp8_f32(v.x, v.y, 0, false);
            pk = __builtin_amdgcn_cvt_pk_fp8_f32(v.z, v.w, pk, true);
            o8[i] = (uint_t)pk;
        }
    }
}

// ---------------- per-bin scatter with inline bin-base scan ----------------
__global__ __launch_bounds__(512) void k_scatter(
    const uint_t* __restrict__ ent_p, const uint_t* __restrict__ ent_u,
    const int* __restrict__ bin_cnt,
    int* __restrict__ off, int* __restrict__ cnt,
    int* __restrict__ src_p, int* __restrict__ src_u) {
    __shared__ int ca[BINSZ];
    __shared__ int cb[BINSZ];
    __shared__ int bb[128];
    int side = blockIdx.y, b = blockIdx.x, t = threadIdx.x;
    const uint_t* E = (side ? ent_u : ent_p) + (size_t)b * BCAP;
    int* src = side ? src_u : src_p;

    if (t < 128) {
        int v = 0;
        if (t < NBIN) { v = bin_cnt[side * NBIN + t]; if (v > BCAP) v = BCAP; }
        bb[t] = v;
    }
    __syncthreads();
    #pragma unroll
    for (int d = 1; d < 128; d <<= 1) {
        int x = 0;
        if (t < 128 && t >= d) x = bb[t - d];
        __syncthreads();
        if (t < 128) bb[t] += x;
        __syncthreads();
    }
    int nb = bin_cnt[side * NBIN + b]; if (nb > BCAP) nb = BCAP;
    int base = bb[b] - nb;

    ca[t] = 0;
    __syncthreads();
    for (int i = t; i < nb; i += 512)
        atomicAdd(&ca[E[i] >> 16], 1);
    __syncthreads();
    int v = ca[t];
    int* A = ca; int* B = cb;
    #pragma unroll
    for (int d = 1; d < BINSZ; d <<= 1) {
        int x = A[t] + ((t >= d) ? A[t - d] : 0);
        B[t] = x;
        __syncthreads();
        int* tmp = A; A = B; B = tmp;
    }
    int excl = A[t] - v;
    B[t] = excl;
    __syncthreads();
    for (int i = t; i < nb; i += 512) {
        uint_t e = E[i];
        int sl = atomicAdd(&B[e >> 16], 1);
        src[base + sl] = (int)(e & 0xffffu);
    }
    int d = (b << BSH) + t;
    if (d < Nn) {
        off[side * Nn + d] = base + excl;
        cnt[side * Nn + d] = v;
    }
}

// ---------------- layer-1 mean aggregation: 8 lanes x uint4 per fp8 row, ILP-4 ----------
// 1 VMEM per gathered 128B row; ILP-4 keeps VGPR <= 64 so 8 waves/SIMD are eligible.
__global__ __launch_bounds__(256, 8) void k_agg1(
    const uint4* __restrict__ xu8, const uint4* __restrict__ xp8,
    const int* __restrict__ off, const int* __restrict__ cnt,
    const int* __restrict__ src_p, const int* __restrict__ src_u,
    us_t* __restrict__ cu, us_t* __restrict__ cp) {
    int side = blockIdx.y;
    const uint4* X = side ? xp8 : xu8;
    const int* of = off + side * Nn;
    const int* cn = cnt + side * Nn;
    const int* sr = side ? src_u : src_p;
    us_t* out = side ? cp : cu;

    int node = blockIdx.x * 32 + (threadIdx.x >> 3);
    if (node >= Nn) return;
    int l = threadIdx.x & 7;
    int s = of[node], c = cn[node];
    float ac[16];
    #pragma unroll
    for (int i = 0; i < 16; ++i) ac[i] = 0.f;

    int j = 0;
    for (; j + 4 <= c; j += 4) {
        int ss[4];
        #pragma unroll
        for (int q = 0; q < 4; ++q) ss[q] = sr[s + j + q];
        uint4 vv[4];
        #pragma unroll
        for (int q = 0; q < 4; ++q) vv[q] = X[(size_t)ss[q] * 8 + l];
        #pragma unroll
        for (int q = 0; q < 4; ++q) {
            const uint_t* pw = reinterpret_cast<const uint_t*>(&vv[q]);
            #pragma unroll
            for (int h = 0; h < 4; ++h) {
                f32x2 plo = __builtin_amdgcn_cvt_pk_f32_fp8((int)pw[h], false);
                f32x2 phi = __builtin_amdgcn_cvt_pk_f32_fp8((int)pw[h], true);
                ac[h * 4 + 0] += plo[0]; ac[h * 4 + 1] += plo[1];
                ac[h * 4 + 2] += phi[0]; ac[h * 4 + 3] += phi[1];
            }
        }
    }
    for (; j < c; ++j) {
        uint4 v0 = X[(size_t)sr[s + j] * 8 + l];
        const uint_t* pw = reinterpret_cast<const uint_t*>(&v0);
        #pragma unroll
        for (int h = 0; h < 4; ++h) {
            f32x2 plo = __builtin_amdgcn_cvt_pk_f32_fp8((int)pw[h], false);
            f32x2 phi = __builtin_amdgcn_cvt_pk_f32_fp8((int)pw[h], true);
            ac[h * 4 + 0] += plo[0]; ac[h * 4 + 1] += plo[1];
            ac[h * 4 + 2] += phi[0]; ac[h * 4 + 3] += phi[1];
        }
    }
    float inv = 1.0f / fmaxf((float)c, 1.0f);
    uint_t ow[8];
    #pragma unroll
    for (int i = 0; i < 8; ++i)
        ow[i] = (uint_t)f2bf(ac[2 * i] * inv) | ((uint_t)f2bf(ac[2 * i + 1] * inv) << 16);
    uint4* dst = reinterpret_cast<uint4*>(out + (size_t)node * 256 + l * 16);
    uint4 o0 = {ow[0], ow[1], ow[2], ow[3]};
    uint4 o1 = {ow[4], ow[5], ow[6], ow[7]};
    dst[0] = o0;
    dst[1] = o1;
}

// ---------------- layer-2 mean aggregation: 8 lanes x uint4 per bf16 row, ILP-4 --------
__global__ __launch_bounds__(256, 8) void k_agg2(
    const uint4* __restrict__ tu, const uint4* __restrict__ tp,
    const int* __restrict__ off, const int* __restrict__ cnt,
    const int* __restrict__ src_p, const int* __restrict__ src_u,
    float* __restrict__ ou, float* __restrict__ op) {
    int side = blockIdx.y;
    const uint4* T = side ? tp : tu;
    const int* of = off + side * Nn;
    const int* cn = cnt + side * Nn;
    const int* sr = side ? src_u : src_p;
    float* out = side ? op : ou;

    int node = blockIdx.x * 32 + (threadIdx.x >> 3);
    if (node >= Nn) return;
    int l = threadIdx.x & 7;
    int s = of[node], c = cn[node];
    float ac[8];
    #pragma unroll
    for (int i = 0; i < 8; ++i) ac[i] = 0.f;

    int j = 0;
    for (; j + 4 <= c; j += 4) {
        int ss[4];
        #pragma unroll
        for (int q = 0; q < 4; ++q) ss[q] = sr[s + j + q];
        uint4 vv[4];
        #pragma unroll
        for (int q = 0; q < 4; ++q) vv[q] = T[(size_t)ss[q] * 8 + l];
        #pragma unroll
        for (int q = 0; q < 4; ++q) {
            const uint_t* pw = reinterpret_cast<const uint_t*>(&vv[q]);
            #pragma unroll
            for (int h = 0; h < 4; ++h) {
                ac[h * 2 + 0] += bflo(pw[h]);
                ac[h * 2 + 1] += bfhi(pw[h]);
            }
        }
    }
    for (; j < c; ++j) {
        uint4 v0 = T[(size_t)sr[s + j] * 8 + l];
        const uint_t* pw = reinterpret_cast<const uint_t*>(&v0);
        #pragma unroll
        for (int h = 0; h < 4; ++h) {
            ac[h * 2 + 0] += bflo(pw[h]);
            ac[h * 2 + 1] += bfhi(pw[h]);
        }
    }
    float inv = 1.0f / fmaxf((float)c, 1.0f);
    float4* po = reinterpret_cast<float4*>(out + (size_t)node * 64) + l * 2;
    float4 p0 = po[0], p1 = po[1];
    p0.x += ac[0] * inv; p0.y += ac[1] * inv; p0.z += ac[2] * inv; p0.w += ac[3] * inv;
    p1.x += ac[4] * inv; p1.y += ac[5] * inv; p1.z += ac[6] * inv; p1.w += ac[7] * inv;
    po[0] = p0; po[1] = p1;
}

// ---------------- A-tile stage: 32 rows x 256 K bf16 = 16 KB, XOR-swizzled ----------------
#define STAGE_A32(Ag, mt, b)                                                        \
    {                                                                               \
        int base_ = (mt) * 32;                                                      \
        _Pragma("unroll")                                                           \
        for (int ii = 0; ii < 2; ++ii) {                                            \
            int s_ = ii * 512 + tid;                                                \
            int row_ = s_ >> 5, ks_ = s_ & 31;                                      \
            int ksl_ = ks_ ^ (row_ & 7);                                            \
            int gr_ = base_ + row_; if (gr_ >= Nn) gr_ = Nn - 1;                    \
            GLOAD((Ag) + (size_t)gr_ * 256 + ksl_ * 8, &sA[b][(s_ - lane) * 8]);    \
        }                                                                           \
    }

// ================= fused layer-1 + layer-2 GEMM, BM=32, depth-2 (round-14 form) ========
__global__ __launch_bounds__(512, 4) void k_mmf(
    const us_t* __restrict__ cu, const us_t* __restrict__ cp,
    const us_t* __restrict__ wc10, const us_t* __restrict__ wc11,
    const us_t* __restrict__ wc20, const us_t* __restrict__ wc21,
    const float* __restrict__ bu1, const float* __restrict__ bp1,
    const float* __restrict__ bu2, const float* __restrict__ bp2,
    us_t* __restrict__ tu, us_t* __restrict__ tp,
    float* __restrict__ ou, float* __restrict__ op) {
    __shared__ us_t sA[3][32 * 256];
    __shared__ us_t sH[32 * SHP];
    int tid = threadIdx.x, lane = tid & 63;
    int wc = tid >> 6;            // wave id 0..7 = N-slot
    int job = blockIdx.y;
    const us_t* Ag = job ? cp : cu;
    const us_t* W1 = job ? wc11 : wc10;
    const us_t* W2 = job ? wc21 : wc20;
    const float* b1 = job ? bp1 : bu1;
    const float* b2 = job ? bu2 : bp2;
    us_t* T = job ? tp : tu;
    float* O = job ? ou : op;

    short8 wf1[2][8];
    #pragma unroll
    for (int n = 0; n < 2; ++n)
        #pragma unroll
        for (int ks = 0; ks < 8; ++ks) {
            int col = wc * 32 + n * 16 + (lane & 15);
            wf1[n][ks] = *reinterpret_cast<const short8*>(
                W1 + (size_t)col * 256 + ks * 32 + (lane >> 4) * 8);
        }
    float bv1[2];
    #pragma unroll
    for (int n = 0; n < 2; ++n) bv1[n] = b1[wc * 32 + n * 16 + (lane & 15)];

    short8 wf2[8];
    #pragma unroll
    for (int ks = 0; ks < 8; ++ks) {
        int col = wc * 16 + (lane & 15);
        wf2[ks] = *reinterpret_cast<const short8*>(
            W2 + (size_t)col * 256 + ks * 32 + (lane >> 4) * 8);
    }
    int col2 = wc * 16 + (lane & 15);
    float bv2 = (col2 >= 64) ? b2[col2 - 64] : 0.f;
    bool top2 = col2 < 64;
    int cc2 = top2 ? col2 : col2 - 64;

    int bx = blockIdx.x;
    int NT = (MT32 - 1 - bx) / GXF + 1;
    STAGE_A32(Ag, bx, 0);
    if (NT > 1) STAGE_A32(Ag, bx + GXF, 1);
    for (int t = 0; t < NT; ++t) {
        int mt = bx + t * GXF;
        if (t + 2 < NT) {
            STAGE_A32(Ag, bx + (t + 2) * GXF, (t + 2) % 3);
            asm volatile("s_waitcnt vmcnt(4)" ::: "memory");   // stage t complete
        } else if (t + 1 < NT) {
            asm volatile("s_waitcnt vmcnt(2)" ::: "memory");
        } else {
            asm volatile("s_waitcnt vmcnt(0)" ::: "memory");
        }
        __syncthreads();
        const us_t* sAc = sA[t % 3];

        // ---- layer-1 MFMAs: 32x32 per wave ----
        f32x4 acc1[2][2];
        #pragma unroll
        for (int m = 0; m < 2; ++m)
            #pragma unroll
            for (int n = 0; n < 2; ++n)
                #pragma unroll
                for (int i = 0; i < 4; ++i) acc1[m][n][i] = 0.f;

        #pragma unroll
        for (int ks = 0; ks < 8; ++ks) {
            short8 af[2];
            #pragma unroll
            for (int m = 0; m < 2; ++m) {
                int row = m * 16 + (lane & 15);
                int sl = (ks * 4 + (lane >> 4)) ^ (row & 7);
                af[m] = *reinterpret_cast<const short8*>(&sAc[row * 256 + sl * 8]);
            }
            #pragma unroll
            for (int m = 0; m < 2; ++m)
                #pragma unroll
                for (int n = 0; n < 2; ++n)
                    acc1[m][n] = __builtin_amdgcn_mfma_f32_16x16x32_bf16(
                        af[m], wf1[n][ks], acc1[m][n], 0, 0, 0);
        }

        // ---- h tile -> LDS (bf16, relu+bias) ----
        #pragma unroll
        for (int n = 0; n < 2; ++n) {
            int col = wc * 32 + n * 16 + (lane & 15);
            #pragma unroll
            for (int m = 0; m < 2; ++m) {
                int r0 = m * 16 + ((lane >> 4) << 2);
                #pragma unroll
                for (int j = 0; j < 4; ++j)
                    sH[(r0 + j) * SHP + col] =
                        f2bf(fmaxf(acc1[m][n][j] + bv1[n], 0.f));
            }
        }
        __syncthreads();

        // ---- layer-2 MFMAs: 32x16 per wave ----
        f32x4 acc2[2];
        #pragma unroll
        for (int m = 0; m < 2; ++m)
            #pragma unroll
            for (int i = 0; i < 4; ++i) acc2[m][i] = 0.f;

        #pragma unroll
        for (int ks = 0; ks < 8; ++ks) {
            short8 af2[2];
            #pragma unroll
            for (int m = 0; m < 2; ++m) {
                int row = m * 16 + (lane & 15);
                af2[m] = *reinterpret_cast<const short8*>(
                    &sH[row * SHP + ks * 32 + (lane >> 4) * 8]);
            }
            #pragma unroll
            for (int m = 0; m < 2; ++m)
                acc2[m] = __builtin_amdgcn_mfma_f32_16x16x32_bf16(
                    af2[m], wf2[ks], acc2[m], 0, 0, 0);
        }

        int mbase = mt * 32;
        #pragma unroll
        for (int m = 0; m < 2; ++m) {
            int row0 = mbase + m * 16 + ((lane >> 4) << 2);
            #pragma unroll
            for (int j = 0; j < 4; ++j) {
                int row = row0 + j;
                if (row >= Nn) continue;
                float v = acc2[m][j] + bv2;
                if (top2) T[(size_t)row * 64 + cc2] = f2bf(v);
                else      O[(size_t)row * 64 + cc2] = v;
            }
        }
    }
}

// ---------------- launch ----------------
extern "C" void kernel_launch(void* const* d_in, const int* in_sizes, int n_in,
                              void* d_out, int out_size, void* d_ws, size_t ws_size,
                              hipStream_t stream) {
    const float* x_user    = (const float*)d_in[0];
    const float* x_product = (const float*)d_in[1];
    const int*   ei        = (const int*)d_in[2];
    const float* w_u1_l = (const float*)d_in[3];
    const float* b_u1   = (const float*)d_in[4];
    const float* w_u1_r = (const float*)d_in[5];
    const float* w_p1_l = (const float*)d_in[6];
    const float* b_p1   = (const float*)d_in[7];
    const float* w_p1_r = (const float*)d_in[8];
    const float* w_u2_l = (const float*)d_in[9];
    const float* b_u2   = (const float*)d_in[10];
    const float* w_u2_r = (const float*)d_in[11];
    const float* w_p2_l = (const float*)d_in[12];
    const float* b_p2   = (const float*)d_in[13];
    const float* w_p2_r = (const float*)d_in[14];

    float* out_u = (float*)d_out;
    float* out_p = out_u + (size_t)Nn * CLSS;

    char* w = (char*)d_ws;
    int* bin_cnt  = (int*)w; w += (size_t)2 * NBIN * 4;
    int* off  = (int*)w;  w += (size_t)2 * Nn * 4;
    int* cnt  = (int*)w;  w += (size_t)2 * Nn * 4;
    int* src_p = (int*)w; w += (size_t)Ee * 4;
    int* src_u = (int*)w; w += (size_t)Ee * 4;
    uint_t* ent_p = (uint_t*)w; w += (size_t)NBIN * BCAP * 4;
    uint_t* ent_u = (uint_t*)w; w += (size_t)NBIN * BCAP * 4;
    uintptr_t a = (uintptr_t)w; a = (a + 255) & ~(uintptr_t)255; w = (char*)a;
    us_t* cu   = (us_t*)w; w += (size_t)Nn * 256 * 2;   // [mean_u | x_prod]
    us_t* cp   = (us_t*)w; w += (size_t)Nn * 256 * 2;   // [mean_p | x_user]
    uint_t* xf8u = (uint_t*)w; w += (size_t)Nn * FIN;
    uint_t* xf8p = (uint_t*)w; w += (size_t)Nn * FIN;
    us_t* tbuf_u = (us_t*)w; w += (size_t)Nn * CLSS * 2;
    us_t* tbuf_p = (us_t*)w; w += (size_t)Nn * CLSS * 2;
    us_t* wc10 = (us_t*)w; w += (size_t)256 * 256 * 2;
    us_t* wc11 = (us_t*)w; w += (size_t)256 * 256 * 2;
    us_t* wc20 = (us_t*)w; w += (size_t)128 * 256 * 2;
    us_t* wc21 = (us_t*)w; w += (size_t)128 * 256 * 2;

    // ---- front-end: zero bin counters, then bin || cvtw || cvtx in one launch ----
    hipMemsetAsync(bin_cnt, 0, (size_t)2 * NBIN * 4, stream);
    k_front<<<NEB + 96 + 512, 512, 0, stream>>>(
        ei, x_user, x_product,
        w_u1_l, w_u1_r, w_p1_l, w_p1_r, w_u2_l, w_u2_r, w_p2_l, w_p2_r,
        cu, cp, xf8u, xf8p, wc10, wc11, wc20, wc21,
        bin_cnt, ent_p, ent_u);
    dim3 gsc(NBIN, 2);
    k_scatter<<<gsc, 512, 0, stream>>>(ent_p, ent_u, bin_cnt,
                                       off, cnt, src_p, src_u);

    // ---- layer 1 aggregation ----
    dim3 ga1((Nn + 31) / 32, 2);
    k_agg1<<<ga1, 256, 0, stream>>>((const uint4*)xf8u, (const uint4*)xf8p,
                                    off, cnt, src_p, src_u, cu, cp);

    // ---- fused layer-1 + layer-2 GEMM ----
    dim3 g1(GXF, 2);
    k_mmf<<<g1, 512, 0, stream>>>(cu, cp, wc10, wc11, wc20, wc21,
                                  b_u1, b_p1, b_u2, b_p2,
                                  tbuf_u, tbuf_p, out_u, out_p);

    // ---- layer 2 aggregation ----
    dim3 ga2((Nn + 31) / 32, 2);
    k_agg2<<<ga2, 256, 0, stream>>>((const uint4*)tbuf_u, (const uint4*)tbuf_p,
                                    off, cnt, src_p, src_u, out_u, out_p);
}

// Round 17
// 175.813 us; speedup vs baseline: 1.0787x; 1.0787x over previous
//
#include <hip/hip_runtime.h>
#include <stdint.h>

#define Nn 50000
#define Ee 800000
#define FIN 128
#define HIDD 256
#define CLSS 64

#define NBIN 98          // ceil(50000 / 512)
#define BSH 9
#define BINSZ 512
#define BCAP 16384
#define EPB 2048
#define NEB ((Ee + EPB - 1) / EPB)   // 391

#define MT32 1563        // ceil(50000/32)
#define GXF 256          // M-group blocks per job for fused GEMM (512 blocks total)

#define SHP 264          // padded sH row stride (us_t)

typedef unsigned int uint_t;
typedef unsigned short us_t;
typedef __attribute__((ext_vector_type(8))) short short8;
typedef __attribute__((ext_vector_type(4))) float f32x4;
typedef __attribute__((ext_vector_type(2))) float f32x2;

__device__ inline float bflo(uint_t v) { union { uint_t u; float f; } c; c.u = v << 16; return c.f; }
__device__ inline float bfhi(uint_t v) { union { uint_t u; float f; } c; c.u = v & 0xffff0000u; return c.f; }
__device__ inline us_t f2bf(float f) {
    union { float f; uint_t u; } c; c.f = f;
    uint_t u = c.u;
    u += 0x7fffu + ((u >> 16) & 1u);
    return (us_t)(u >> 16);
}

#define GLOAD(gp, lp)                                                      \
    __builtin_amdgcn_global_load_lds(                                      \
        (const __attribute__((address_space(1))) unsigned int*)(gp),       \
        (__attribute__((address_space(3))) unsigned int*)(lp), 16, 0, 0)

// ================= merged front-end: k_bin || cvtw || cvtx =================
__global__ __launch_bounds__(512) void k_front(
    const int* __restrict__ ei,
    const float* __restrict__ xu, const float* __restrict__ xp,
    const float* __restrict__ w1, const float* __restrict__ w2,
    const float* __restrict__ w3, const float* __restrict__ w4,
    const float* __restrict__ w5, const float* __restrict__ w6,
    const float* __restrict__ w7, const float* __restrict__ w8,
    us_t* __restrict__ cu, us_t* __restrict__ cp,
    uint_t* __restrict__ f8u, uint_t* __restrict__ f8p,
    us_t* __restrict__ wc10, us_t* __restrict__ wc11,
    us_t* __restrict__ wc20, us_t* __restrict__ wc21,
    int* __restrict__ bin_cnt,
    uint_t* __restrict__ ent_p, uint_t* __restrict__ ent_u) {
    __shared__ int hist[2 * NBIN];
    __shared__ int base[2 * NBIN];
    int bx = blockIdx.x, tid = threadIdx.x;

    if (bx < NEB) {
        int e0 = bx * EPB;
        int n = Ee - e0; if (n > EPB) n = EPB;
        for (int i = tid; i < 2 * NBIN; i += 512) hist[i] = 0;
        __syncthreads();
        for (int i = tid; i < n; i += 512) {
            int u = ei[e0 + i], p = ei[Ee + e0 + i];
            atomicAdd(&hist[p >> BSH], 1);
            atomicAdd(&hist[NBIN + (u >> BSH)], 1);
        }
        __syncthreads();
        for (int i = tid; i < 2 * NBIN; i += 512) {
            int c = hist[i];
            base[i] = c ? atomicAdd(&bin_cnt[i], c) : 0;
        }
        __syncthreads();
        for (int i = tid; i < 2 * NBIN; i += 512) hist[i] = base[i];
        __syncthreads();
        for (int i = tid; i < n; i += 512) {
            int u = ei[e0 + i], p = ei[Ee + e0 + i];
            int bp = p >> BSH, bu = u >> BSH;
            int rp = atomicAdd(&hist[bp], 1);
            if (rp < BCAP)
                ent_p[(size_t)bp * BCAP + rp] = ((uint_t)(p & (BINSZ - 1)) << 16) | (uint_t)u;
            int ru = atomicAdd(&hist[NBIN + bu], 1);
            if (ru < BCAP)
                ent_u[(size_t)bu * BCAP + ru] = ((uint_t)(u & (BINSZ - 1)) << 16) | (uint_t)p;
        }
    } else if (bx < NEB + 96) {
        int i = (bx - NEB) * 512 + tid;
        const float* wp; us_t* dst;
        if (i < 32768) {
            int seg = i >> 13; int loc = i & 8191;
            int row = loc >> 5, col = (loc & 31) * 4;
            switch (seg) {
                case 0: wp = w1; dst = wc10 + (size_t)row * 256 + col; break;
                case 1: wp = w2; dst = wc10 + (size_t)row * 256 + 128 + col; break;
                case 2: wp = w3; dst = wc11 + (size_t)row * 256 + col; break;
                default: wp = w4; dst = wc11 + (size_t)row * 256 + 128 + col; break;
            }
            float4 v = reinterpret_cast<const float4*>(wp)[i & 8191];
            ushort4 o;
            o.x = f2bf(v.x); o.y = f2bf(v.y); o.z = f2bf(v.z); o.w = f2bf(v.w);
            *reinterpret_cast<ushort4*>(dst) = o;
        } else {
            int j = i - 32768;
            int seg = j >> 12; int loc = j & 4095;
            switch (seg) {
                case 0: wp = w5; dst = wc20; break;
                case 1: wp = w6; dst = wc21 + 64 * 256; break;
                case 2: wp = w7; dst = wc21; break;
                default: wp = w8; dst = wc20 + 64 * 256; break;
            }
            float4 v = reinterpret_cast<const float4*>(wp)[loc];
            ushort4 o;
            o.x = f2bf(v.x); o.y = f2bf(v.y); o.z = f2bf(v.z); o.w = f2bf(v.w);
            reinterpret_cast<ushort4*>(dst)[loc] = o;
        }
    } else {
        int bcx = bx - NEB - 96;
        int side = bcx & 1;
        const float* in = side ? xp : xu;
        us_t* comb = side ? cu : cp;
        uint_t* o8 = side ? f8p : f8u;
        const int n4 = (Nn * FIN) / 4;
        int i = (bcx >> 1) * 512 + tid;
        int stride = 256 * 512;
        for (; i < n4; i += stride) {
            float4 v = reinterpret_cast<const float4*>(in)[i];
            ushort4 o;
            o.x = f2bf(v.x); o.y = f2bf(v.y); o.z = f2bf(v.z); o.w = f2bf(v.w);
            int node = i >> 5;
            int col = (i & 31) * 4;
            *reinterpret_cast<ushort4*>(comb + (size_t)node * 256 + 128 + col) = o;
            int pk = __builtin_amdgcn_cvt_pk_fp8_f32(v.x, v.y, 0, false);
            pk = __builtin_amdgcn_cvt_pk_fp8_f32(v.z, v.w, pk, true);
            o8[i] = (uint_t)pk;
        }
    }
}

// ---------------- per-bin scatter with inline bin-base scan ----------------
__global__ __launch_bounds__(512) void k_scatter(
    const uint_t* __restrict__ ent_p, const uint_t* __restrict__ ent_u,
    const int* __restrict__ bin_cnt,
    int* __restrict__ off, int* __restrict__ cnt,
    int* __restrict__ src_p, int* __restrict__ src_u) {
    __shared__ int ca[BINSZ];
    __shared__ int cb[BINSZ];
    __shared__ int bb[128];
    int side = blockIdx.y, b = blockIdx.x, t = threadIdx.x;
    const uint_t* E = (side ? ent_u : ent_p) + (size_t)b * BCAP;
    int* src = side ? src_u : src_p;

    if (t < 128) {
        int v = 0;
        if (t < NBIN) { v = bin_cnt[side * NBIN + t]; if (v > BCAP) v = BCAP; }
        bb[t] = v;
    }
    __syncthreads();
    #pragma unroll
    for (int d = 1; d < 128; d <<= 1) {
        int x = 0;
        if (t < 128 && t >= d) x = bb[t - d];
        __syncthreads();
        if (t < 128) bb[t] += x;
        __syncthreads();
    }
    int nb = bin_cnt[side * NBIN + b]; if (nb > BCAP) nb = BCAP;
    int base = bb[b] - nb;

    ca[t] = 0;
    __syncthreads();
    for (int i = t; i < nb; i += 512)
        atomicAdd(&ca[E[i] >> 16], 1);
    __syncthreads();
    int v = ca[t];
    int* A = ca; int* B = cb;
    #pragma unroll
    for (int d = 1; d < BINSZ; d <<= 1) {
        int x = A[t] + ((t >= d) ? A[t - d] : 0);
        B[t] = x;
        __syncthreads();
        int* tmp = A; A = B; B = tmp;
    }
    int excl = A[t] - v;
    B[t] = excl;
    __syncthreads();
    for (int i = t; i < nb; i += 512) {
        uint_t e = E[i];
        int sl = atomicAdd(&B[e >> 16], 1);
        src[base + sl] = (int)(e & 0xffffu);
    }
    int d = (b << BSH) + t;
    if (d < Nn) {
        off[side * Nn + d] = base + excl;
        cnt[side * Nn + d] = v;
    }
}

// ---------------- layer-1 mean aggregation: 8 lanes x uint4 per fp8 row, ILP-8 ---------
__global__ __launch_bounds__(256) void k_agg1(
    const uint4* __restrict__ xu8, const uint4* __restrict__ xp8,
    const int* __restrict__ off, const int* __restrict__ cnt,
    const int* __restrict__ src_p, const int* __restrict__ src_u,
    us_t* __restrict__ cu, us_t* __restrict__ cp) {
    int side = blockIdx.y;
    const uint4* X = side ? xp8 : xu8;
    const int* of = off + side * Nn;
    const int* cn = cnt + side * Nn;
    const int* sr = side ? src_u : src_p;
    us_t* out = side ? cp : cu;

    int node = blockIdx.x * 32 + (threadIdx.x >> 3);
    if (node >= Nn) return;
    int l = threadIdx.x & 7;
    int s = of[node], c = cn[node];
    float ac[16];
    #pragma unroll
    for (int i = 0; i < 16; ++i) ac[i] = 0.f;

    int j = 0;
    for (; j + 8 <= c; j += 8) {
        int ss[8];
        #pragma unroll
        for (int q = 0; q < 8; ++q) ss[q] = sr[s + j + q];
        uint4 vv[8];
        #pragma unroll
        for (int q = 0; q < 8; ++q) vv[q] = X[(size_t)ss[q] * 8 + l];
        #pragma unroll
        for (int q = 0; q < 8; ++q) {
            const uint_t* pw = reinterpret_cast<const uint_t*>(&vv[q]);
            #pragma unroll
            for (int h = 0; h < 4; ++h) {
                f32x2 plo = __builtin_amdgcn_cvt_pk_f32_fp8((int)pw[h], false);
                f32x2 phi = __builtin_amdgcn_cvt_pk_f32_fp8((int)pw[h], true);
                ac[h * 4 + 0] += plo[0]; ac[h * 4 + 1] += plo[1];
                ac[h * 4 + 2] += phi[0]; ac[h * 4 + 3] += phi[1];
            }
        }
    }
    for (; j < c; ++j) {
        uint4 v0 = X[(size_t)sr[s + j] * 8 + l];
        const uint_t* pw = reinterpret_cast<const uint_t*>(&v0);
        #pragma unroll
        for (int h = 0; h < 4; ++h) {
            f32x2 plo = __builtin_amdgcn_cvt_pk_f32_fp8((int)pw[h], false);
            f32x2 phi = __builtin_amdgcn_cvt_pk_f32_fp8((int)pw[h], true);
            ac[h * 4 + 0] += plo[0]; ac[h * 4 + 1] += plo[1];
            ac[h * 4 + 2] += phi[0]; ac[h * 4 + 3] += phi[1];
        }
    }
    float inv = 1.0f / fmaxf((float)c, 1.0f);
    uint_t ow[8];
    #pragma unroll
    for (int i = 0; i < 8; ++i)
        ow[i] = (uint_t)f2bf(ac[2 * i] * inv) | ((uint_t)f2bf(ac[2 * i + 1] * inv) << 16);
    uint4* dst = reinterpret_cast<uint4*>(out + (size_t)node * 256 + l * 16);
    uint4 o0 = {ow[0], ow[1], ow[2], ow[3]};
    uint4 o1 = {ow[4], ow[5], ow[6], ow[7]};
    dst[0] = o0;
    dst[1] = o1;
}

// ---------------- layer-2 mean aggregation: 8 lanes x uint4 per bf16 row, ILP-8 --------
__global__ __launch_bounds__(256) void k_agg2(
    const uint4* __restrict__ tu, const uint4* __restrict__ tp,
    const int* __restrict__ off, const int* __restrict__ cnt,
    const int* __restrict__ src_p, const int* __restrict__ src_u,
    float* __restrict__ ou, float* __restrict__ op) {
    int side = blockIdx.y;
    const uint4* T = side ? tp : tu;
    const int* of = off + side * Nn;
    const int* cn = cnt + side * Nn;
    const int* sr = side ? src_u : src_p;
    float* out = side ? op : ou;

    int node = blockIdx.x * 32 + (threadIdx.x >> 3);
    if (node >= Nn) return;
    int l = threadIdx.x & 7;
    int s = of[node], c = cn[node];
    float ac[8];
    #pragma unroll
    for (int i = 0; i < 8; ++i) ac[i] = 0.f;

    int j = 0;
    for (; j + 8 <= c; j += 8) {
        int ss[8];
        #pragma unroll
        for (int q = 0; q < 8; ++q) ss[q] = sr[s + j + q];
        uint4 vv[8];
        #pragma unroll
        for (int q = 0; q < 8; ++q) vv[q] = T[(size_t)ss[q] * 8 + l];
        #pragma unroll
        for (int q = 0; q < 8; ++q) {
            const uint_t* pw = reinterpret_cast<const uint_t*>(&vv[q]);
            #pragma unroll
            for (int h = 0; h < 4; ++h) {
                ac[h * 2 + 0] += bflo(pw[h]);
                ac[h * 2 + 1] += bfhi(pw[h]);
            }
        }
    }
    for (; j < c; ++j) {
        uint4 v0 = T[(size_t)sr[s + j] * 8 + l];
        const uint_t* pw = reinterpret_cast<const uint_t*>(&v0);
        #pragma unroll
        for (int h = 0; h < 4; ++h) {
            ac[h * 2 + 0] += bflo(pw[h]);
            ac[h * 2 + 1] += bfhi(pw[h]);
        }
    }
    float inv = 1.0f / fmaxf((float)c, 1.0f);
    float4* po = reinterpret_cast<float4*>(out + (size_t)node * 64) + l * 2;
    float4 p0 = po[0], p1 = po[1];
    p0.x += ac[0] * inv; p0.y += ac[1] * inv; p0.z += ac[2] * inv; p0.w += ac[3] * inv;
    p1.x += ac[4] * inv; p1.y += ac[5] * inv; p1.z += ac[6] * inv; p1.w += ac[7] * inv;
    po[0] = p0; po[1] = p1;
}

// ---------------- A-tile stage: 32 rows x 256 K bf16 = 16 KB, XOR-swizzled ----------------
#define STAGE_A32(Ag, mt, b)                                                        \
    {                                                                               \
        int base_ = (mt) * 32;                                                      \
        _Pragma("unroll")                                                           \
        for (int ii = 0; ii < 2; ++ii) {                                            \
            int s_ = ii * 512 + tid;                                                \
            int row_ = s_ >> 5, ks_ = s_ & 31;                                      \
            int ksl_ = ks_ ^ (row_ & 7);                                            \
            int gr_ = base_ + row_; if (gr_ >= Nn) gr_ = Nn - 1;                    \
            GLOAD((Ag) + (size_t)gr_ * 256 + ksl_ * 8, &sA[b][(s_ - lane) * 8]);    \
        }                                                                           \
    }

// ================= fused layer-1 + layer-2 GEMM, BM=32, depth-2 (round-14 form) ========
__global__ __launch_bounds__(512, 4) void k_mmf(
    const us_t* __restrict__ cu, const us_t* __restrict__ cp,
    const us_t* __restrict__ wc10, const us_t* __restrict__ wc11,
    const us_t* __restrict__ wc20, const us_t* __restrict__ wc21,
    const float* __restrict__ bu1, const float* __restrict__ bp1,
    const float* __restrict__ bu2, const float* __restrict__ bp2,
    us_t* __restrict__ tu, us_t* __restrict__ tp,
    float* __restrict__ ou, float* __restrict__ op) {
    __shared__ us_t sA[3][32 * 256];
    __shared__ us_t sH[32 * SHP];
    int tid = threadIdx.x, lane = tid & 63;
    int wc = tid >> 6;            // wave id 0..7 = N-slot
    int job = blockIdx.y;
    const us_t* Ag = job ? cp : cu;
    const us_t* W1 = job ? wc11 : wc10;
    const us_t* W2 = job ? wc21 : wc20;
    const float* b1 = job ? bp1 : bu1;
    const float* b2 = job ? bu2 : bp2;
    us_t* T = job ? tp : tu;
    float* O = job ? ou : op;

    short8 wf1[2][8];
    #pragma unroll
    for (int n = 0; n < 2; ++n)
        #pragma unroll
        for (int ks = 0; ks < 8; ++ks) {
            int col = wc * 32 + n * 16 + (lane & 15);
            wf1[n][ks] = *reinterpret_cast<const short8*>(
                W1 + (size_t)col * 256 + ks * 32 + (lane >> 4) * 8);
        }
    float bv1[2];
    #pragma unroll
    for (int n = 0; n < 2; ++n) bv1[n] = b1[wc * 32 + n * 16 + (lane & 15)];

    short8 wf2[8];
    #pragma unroll
    for (int ks = 0; ks < 8; ++ks) {
        int col = wc * 16 + (lane & 15);
        wf2[ks] = *reinterpret_cast<const short8*>(
            W2 + (size_t)col * 256 + ks * 32 + (lane >> 4) * 8);
    }
    int col2 = wc * 16 + (lane & 15);
    float bv2 = (col2 >= 64) ? b2[col2 - 64] : 0.f;
    bool top2 = col2 < 64;
    int cc2 = top2 ? col2 : col2 - 64;

    int bx = blockIdx.x;
    int NT = (MT32 - 1 - bx) / GXF + 1;
    STAGE_A32(Ag, bx, 0);
    if (NT > 1) STAGE_A32(Ag, bx + GXF, 1);
    for (int t = 0; t < NT; ++t) {
        int mt = bx + t * GXF;
        if (t + 2 < NT) {
            STAGE_A32(Ag, bx + (t + 2) * GXF, (t + 2) % 3);
            asm volatile("s_waitcnt vmcnt(4)" ::: "memory");   // stage t complete
        } else if (t + 1 < NT) {
            asm volatile("s_waitcnt vmcnt(2)" ::: "memory");
        } else {
            asm volatile("s_waitcnt vmcnt(0)" ::: "memory");
        }
        __syncthreads();
        const us_t* sAc = sA[t % 3];

        // ---- layer-1 MFMAs: 32x32 per wave ----
        f32x4 acc1[2][2];
        #pragma unroll
        for (int m = 0; m < 2; ++m)
            #pragma unroll
            for (int n = 0; n < 2; ++n)
                #pragma unroll
                for (int i = 0; i < 4; ++i) acc1[m][n][i] = 0.f;

        #pragma unroll
        for (int ks = 0; ks < 8; ++ks) {
            short8 af[2];
            #pragma unroll
            for (int m = 0; m < 2; ++m) {
                int row = m * 16 + (lane & 15);
                int sl = (ks * 4 + (lane >> 4)) ^ (row & 7);
                af[m] = *reinterpret_cast<const short8*>(&sAc[row * 256 + sl * 8]);
            }
            #pragma unroll
            for (int m = 0; m < 2; ++m)
                #pragma unroll
                for (int n = 0; n < 2; ++n)
                    acc1[m][n] = __builtin_amdgcn_mfma_f32_16x16x32_bf16(
                        af[m], wf1[n][ks], acc1[m][n], 0, 0, 0);
        }

        // ---- h tile -> LDS (bf16, relu+bias) ----
        #pragma unroll
        for (int n = 0; n < 2; ++n) {
            int col = wc * 32 + n * 16 + (lane & 15);
            #pragma unroll
            for (int m = 0; m < 2; ++m) {
                int r0 = m * 16 + ((lane >> 4) << 2);
                #pragma unroll
                for (int j = 0; j < 4; ++j)
                    sH[(r0 + j) * SHP + col] =
                        f2bf(fmaxf(acc1[m][n][j] + bv1[n], 0.f));
            }
        }
        __syncthreads();

        // ---- layer-2 MFMAs: 32x16 per wave ----
        f32x4 acc2[2];
        #pragma unroll
        for (int m = 0; m < 2; ++m)
            #pragma unroll
            for (int i = 0; i < 4; ++i) acc2[m][i] = 0.f;

        #pragma unroll
        for (int ks = 0; ks < 8; ++ks) {
            short8 af2[2];
            #pragma unroll
            for (int m = 0; m < 2; ++m) {
                int row = m * 16 + (lane & 15);
                af2[m] = *reinterpret_cast<const short8*>(
                    &sH[row * SHP + ks * 32 + (lane >> 4) * 8]);
            }
            #pragma unroll
            for (int m = 0; m < 2; ++m)
                acc2[m] = __builtin_amdgcn_mfma_f32_16x16x32_bf16(
                    af2[m], wf2[ks], acc2[m], 0, 0, 0);
        }

        int mbase = mt * 32;
        #pragma unroll
        for (int m = 0; m < 2; ++m) {
            int row0 = mbase + m * 16 + ((lane >> 4) << 2);
            #pragma unroll
            for (int j = 0; j < 4; ++j) {
                int row = row0 + j;
                if (row >= Nn) continue;
                float v = acc2[m][j] + bv2;
                if (top2) T[(size_t)row * 64 + cc2] = f2bf(v);
                else      O[(size_t)row * 64 + cc2] = v;
            }
        }
    }
}

// ---------------- launch ----------------
extern "C" void kernel_launch(void* const* d_in, const int* in_sizes, int n_in,
                              void* d_out, int out_size, void* d_ws, size_t ws_size,
                              hipStream_t stream) {
    const float* x_user    = (const float*)d_in[0];
    const float* x_product = (const float*)d_in[1];
    const int*   ei        = (const int*)d_in[2];
    const float* w_u1_l = (const float*)d_in[3];
    const float* b_u1   = (const float*)d_in[4];
    const float* w_u1_r = (const float*)d_in[5];
    const float* w_p1_l = (const float*)d_in[6];
    const float* b_p1   = (const float*)d_in[7];
    const float* w_p1_r = (const float*)d_in[8];
    const float* w_u2_l = (const float*)d_in[9];
    const float* b_u2   = (const float*)d_in[10];
    const float* w_u2_r = (const float*)d_in[11];
    const float* w_p2_l = (const float*)d_in[12];
    const float* b_p2   = (const float*)d_in[13];
    const float* w_p2_r = (const float*)d_in[14];

    float* out_u = (float*)d_out;
    float* out_p = out_u + (size_t)Nn * CLSS;

    char* w = (char*)d_ws;
    int* bin_cnt  = (int*)w; w += (size_t)2 * NBIN * 4;
    int* off  = (int*)w;  w += (size_t)2 * Nn * 4;
    int* cnt  = (int*)w;  w += (size_t)2 * Nn * 4;
    int* src_p = (int*)w; w += (size_t)Ee * 4;
    int* src_u = (int*)w; w += (size_t)Ee * 4;
    uint_t* ent_p = (uint_t*)w; w += (size_t)NBIN * BCAP * 4;
    uint_t* ent_u = (uint_t*)w; w += (size_t)NBIN * BCAP * 4;
    uintptr_t a = (uintptr_t)w; a = (a + 255) & ~(uintptr_t)255; w = (char*)a;
    us_t* cu   = (us_t*)w; w += (size_t)Nn * 256 * 2;   // [mean_u | x_prod]
    us_t* cp   = (us_t*)w; w += (size_t)Nn * 256 * 2;   // [mean_p | x_user]
    uint_t* xf8u = (uint_t*)w; w += (size_t)Nn * FIN;
    uint_t* xf8p = (uint_t*)w; w += (size_t)Nn * FIN;
    us_t* tbuf_u = (us_t*)w; w += (size_t)Nn * CLSS * 2;
    us_t* tbuf_p = (us_t*)w; w += (size_t)Nn * CLSS * 2;
    us_t* wc10 = (us_t*)w; w += (size_t)256 * 256 * 2;
    us_t* wc11 = (us_t*)w; w += (size_t)256 * 256 * 2;
    us_t* wc20 = (us_t*)w; w += (size_t)128 * 256 * 2;
    us_t* wc21 = (us_t*)w; w += (size_t)128 * 256 * 2;

    // ---- front-end: zero bin counters, then bin || cvtw || cvtx in one launch ----
    hipMemsetAsync(bin_cnt, 0, (size_t)2 * NBIN * 4, stream);
    k_front<<<NEB + 96 + 512, 512, 0, stream>>>(
        ei, x_user, x_product,
        w_u1_l, w_u1_r, w_p1_l, w_p1_r, w_u2_l, w_u2_r, w_p2_l, w_p2_r,
        cu, cp, xf8u, xf8p, wc10, wc11, wc20, wc21,
        bin_cnt, ent_p, ent_u);
    dim3 gsc(NBIN, 2);
    k_scatter<<<gsc, 512, 0, stream>>>(ent_p, ent_u, bin_cnt,
                                       off, cnt, src_p, src_u);

    // ---- layer 1 aggregation ----
    dim3 ga1((Nn + 31) / 32, 2);
    k_agg1<<<ga1, 256, 0, stream>>>((const uint4*)xf8u, (const uint4*)xf8p,
                                    off, cnt, src_p, src_u, cu, cp);

    // ---- fused layer-1 + layer-2 GEMM ----
    dim3 g1(GXF, 2);
    k_mmf<<<g1, 512, 0, stream>>>(cu, cp, wc10, wc11, wc20, wc21,
                                  b_u1, b_p1, b_u2, b_p2,
                                  tbuf_u, tbuf_p, out_u, out_p);

    // ---- layer 2 aggregation ----
    dim3 ga2((Nn + 31) / 32, 2);
    k_agg2<<<ga2, 256, 0, stream>>>((const uint4*)tbuf_u, (const uint4*)tbuf_p,
                                    off, cnt, src_p, src_u, out_u, out_p);
}

// Round 18
// 175.303 us; speedup vs baseline: 1.0819x; 1.0029x over previous
//
#include <hip/hip_runtime.h>
#include <stdint.h>

#define Nn 50000
#define Ee 800000
#define FIN 128
#define HIDD 256
#define CLSS 64

#define NBIN 98          // ceil(50000 / 512)
#define BSH 9
#define BINSZ 512
#define BCAP 16384
#define EPB 2048
#define NEB ((Ee + EPB - 1) / EPB)   // 391

#define MT32 1563        // ceil(50000/32)
#define GXF 256          // M-group blocks per job for fused GEMM (512 blocks total); NT = 6 or 7

#define SHP 264          // padded sH row stride (us_t)

typedef unsigned int uint_t;
typedef unsigned short us_t;
typedef __attribute__((ext_vector_type(8))) short short8;
typedef __attribute__((ext_vector_type(4))) float f32x4;
typedef __attribute__((ext_vector_type(2))) float f32x2;

__device__ inline float bflo(uint_t v) { union { uint_t u; float f; } c; c.u = v << 16; return c.f; }
__device__ inline float bfhi(uint_t v) { union { uint_t u; float f; } c; c.u = v & 0xffff0000u; return c.f; }
__device__ inline us_t f2bf(float f) {
    union { float f; uint_t u; } c; c.f = f;
    uint_t u = c.u;
    u += 0x7fffu + ((u >> 16) & 1u);
    return (us_t)(u >> 16);
}

#define GLOAD(gp, lp)                                                      \
    __builtin_amdgcn_global_load_lds(                                      \
        (const __attribute__((address_space(1))) unsigned int*)(gp),       \
        (__attribute__((address_space(3))) unsigned int*)(lp), 16, 0, 0)

// ================= merged front-end: k_bin || cvtw || cvtx =================
__global__ __launch_bounds__(512) void k_front(
    const int* __restrict__ ei,
    const float* __restrict__ xu, const float* __restrict__ xp,
    const float* __restrict__ w1, const float* __restrict__ w2,
    const float* __restrict__ w3, const float* __restrict__ w4,
    const float* __restrict__ w5, const float* __restrict__ w6,
    const float* __restrict__ w7, const float* __restrict__ w8,
    us_t* __restrict__ cu, us_t* __restrict__ cp,
    uint_t* __restrict__ f8u, uint_t* __restrict__ f8p,
    us_t* __restrict__ wc10, us_t* __restrict__ wc11,
    us_t* __restrict__ wc20, us_t* __restrict__ wc21,
    int* __restrict__ bin_cnt,
    uint_t* __restrict__ ent_p, uint_t* __restrict__ ent_u) {
    __shared__ int hist[2 * NBIN];
    __shared__ int base[2 * NBIN];
    int bx = blockIdx.x, tid = threadIdx.x;

    if (bx < NEB) {
        int e0 = bx * EPB;
        int n = Ee - e0; if (n > EPB) n = EPB;
        for (int i = tid; i < 2 * NBIN; i += 512) hist[i] = 0;
        __syncthreads();
        for (int i = tid; i < n; i += 512) {
            int u = ei[e0 + i], p = ei[Ee + e0 + i];
            atomicAdd(&hist[p >> BSH], 1);
            atomicAdd(&hist[NBIN + (u >> BSH)], 1);
        }
        __syncthreads();
        for (int i = tid; i < 2 * NBIN; i += 512) {
            int c = hist[i];
            base[i] = c ? atomicAdd(&bin_cnt[i], c) : 0;
        }
        __syncthreads();
        for (int i = tid; i < 2 * NBIN; i += 512) hist[i] = base[i];
        __syncthreads();
        for (int i = tid; i < n; i += 512) {
            int u = ei[e0 + i], p = ei[Ee + e0 + i];
            int bp = p >> BSH, bu = u >> BSH;
            int rp = atomicAdd(&hist[bp], 1);
            if (rp < BCAP)
                ent_p[(size_t)bp * BCAP + rp] = ((uint_t)(p & (BINSZ - 1)) << 16) | (uint_t)u;
            int ru = atomicAdd(&hist[NBIN + bu], 1);
            if (ru < BCAP)
                ent_u[(size_t)bu * BCAP + ru] = ((uint_t)(u & (BINSZ - 1)) << 16) | (uint_t)p;
        }
    } else if (bx < NEB + 96) {
        int i = (bx - NEB) * 512 + tid;
        const float* wp; us_t* dst;
        if (i < 32768) {
            int seg = i >> 13; int loc = i & 8191;
            int row = loc >> 5, col = (loc & 31) * 4;
            switch (seg) {
                case 0: wp = w1; dst = wc10 + (size_t)row * 256 + col; break;
                case 1: wp = w2; dst = wc10 + (size_t)row * 256 + 128 + col; break;
                case 2: wp = w3; dst = wc11 + (size_t)row * 256 + col; break;
                default: wp = w4; dst = wc11 + (size_t)row * 256 + 128 + col; break;
            }
            float4 v = reinterpret_cast<const float4*>(wp)[i & 8191];
            ushort4 o;
            o.x = f2bf(v.x); o.y = f2bf(v.y); o.z = f2bf(v.z); o.w = f2bf(v.w);
            *reinterpret_cast<ushort4*>(dst) = o;
        } else {
            int j = i - 32768;
            int seg = j >> 12; int loc = j & 4095;
            switch (seg) {
                case 0: wp = w5; dst = wc20; break;
                case 1: wp = w6; dst = wc21 + 64 * 256; break;
                case 2: wp = w7; dst = wc21; break;
                default: wp = w8; dst = wc20 + 64 * 256; break;
            }
            float4 v = reinterpret_cast<const float4*>(wp)[loc];
            ushort4 o;
            o.x = f2bf(v.x); o.y = f2bf(v.y); o.z = f2bf(v.z); o.w = f2bf(v.w);
            reinterpret_cast<ushort4*>(dst)[loc] = o;
        }
    } else {
        int bcx = bx - NEB - 96;
        int side = bcx & 1;
        const float* in = side ? xp : xu;
        us_t* comb = side ? cu : cp;
        uint_t* o8 = side ? f8p : f8u;
        const int n4 = (Nn * FIN) / 4;
        int i = (bcx >> 1) * 512 + tid;
        int stride = 256 * 512;
        for (; i < n4; i += stride) {
            float4 v = reinterpret_cast<const float4*>(in)[i];
            ushort4 o;
            o.x = f2bf(v.x); o.y = f2bf(v.y); o.z = f2bf(v.z); o.w = f2bf(v.w);
            int node = i >> 5;
            int col = (i & 31) * 4;
            *reinterpret_cast<ushort4*>(comb + (size_t)node * 256 + 128 + col) = o;
            int pk = __builtin_amdgcn_cvt_pk_fp8_f32(v.x, v.y, 0, false);
            pk = __builtin_amdgcn_cvt_pk_fp8_f32(v.z, v.w, pk, true);
            o8[i] = (uint_t)pk;
        }
    }
}

// ---------------- per-bin scatter with inline bin-base scan ----------------
__global__ __launch_bounds__(512) void k_scatter(
    const uint_t* __restrict__ ent_p, const uint_t* __restrict__ ent_u,
    const int* __restrict__ bin_cnt,
    int* __restrict__ off, int* __restrict__ cnt,
    int* __restrict__ src_p, int* __restrict__ src_u) {
    __shared__ int ca[BINSZ];
    __shared__ int cb[BINSZ];
    __shared__ int bb[128];
    int side = blockIdx.y, b = blockIdx.x, t = threadIdx.x;
    const uint_t* E = (side ? ent_u : ent_p) + (size_t)b * BCAP;
    int* src = side ? src_u : src_p;

    if (t < 128) {
        int v = 0;
        if (t < NBIN) { v = bin_cnt[side * NBIN + t]; if (v > BCAP) v = BCAP; }
        bb[t] = v;
    }
    __syncthreads();
    #pragma unroll
    for (int d = 1; d < 128; d <<= 1) {
        int x = 0;
        if (t < 128 && t >= d) x = bb[t - d];
        __syncthreads();
        if (t < 128) bb[t] += x;
        __syncthreads();
    }
    int nb = bin_cnt[side * NBIN + b]; if (nb > BCAP) nb = BCAP;
    int base = bb[b] - nb;

    ca[t] = 0;
    __syncthreads();
    for (int i = t; i < nb; i += 512)
        atomicAdd(&ca[E[i] >> 16], 1);
    __syncthreads();
    int v = ca[t];
    int* A = ca; int* B = cb;
    #pragma unroll
    for (int d = 1; d < BINSZ; d <<= 1) {
        int x = A[t] + ((t >= d) ? A[t - d] : 0);
        B[t] = x;
        __syncthreads();
        int* tmp = A; A = B; B = tmp;
    }
    int excl = A[t] - v;
    B[t] = excl;
    __syncthreads();
    for (int i = t; i < nb; i += 512) {
        uint_t e = E[i];
        int sl = atomicAdd(&B[e >> 16], 1);
        src[base + sl] = (int)(e & 0xffffu);
    }
    int d = (b << BSH) + t;
    if (d < Nn) {
        off[side * Nn + d] = base + excl;
        cnt[side * Nn + d] = v;
    }
}

// ---------------- layer-1 mean aggregation: 8 lanes x uint4 per fp8 row, ILP-8 ---------
__global__ __launch_bounds__(256) void k_agg1(
    const uint4* __restrict__ xu8, const uint4* __restrict__ xp8,
    const int* __restrict__ off, const int* __restrict__ cnt,
    const int* __restrict__ src_p, const int* __restrict__ src_u,
    us_t* __restrict__ cu, us_t* __restrict__ cp) {
    int side = blockIdx.y;
    const uint4* X = side ? xp8 : xu8;
    const int* of = off + side * Nn;
    const int* cn = cnt + side * Nn;
    const int* sr = side ? src_u : src_p;
    us_t* out = side ? cp : cu;

    int node = blockIdx.x * 32 + (threadIdx.x >> 3);
    if (node >= Nn) return;
    int l = threadIdx.x & 7;
    int s = of[node], c = cn[node];
    float ac[16];
    #pragma unroll
    for (int i = 0; i < 16; ++i) ac[i] = 0.f;

    int j = 0;
    for (; j + 8 <= c; j += 8) {
        int ss[8];
        #pragma unroll
        for (int q = 0; q < 8; ++q) ss[q] = sr[s + j + q];
        uint4 vv[8];
        #pragma unroll
        for (int q = 0; q < 8; ++q) vv[q] = X[(size_t)ss[q] * 8 + l];
        #pragma unroll
        for (int q = 0; q < 8; ++q) {
            const uint_t* pw = reinterpret_cast<const uint_t*>(&vv[q]);
            #pragma unroll
            for (int h = 0; h < 4; ++h) {
                f32x2 plo = __builtin_amdgcn_cvt_pk_f32_fp8((int)pw[h], false);
                f32x2 phi = __builtin_amdgcn_cvt_pk_f32_fp8((int)pw[h], true);
                ac[h * 4 + 0] += plo[0]; ac[h * 4 + 1] += plo[1];
                ac[h * 4 + 2] += phi[0]; ac[h * 4 + 3] += phi[1];
            }
        }
    }
    for (; j < c; ++j) {
        uint4 v0 = X[(size_t)sr[s + j] * 8 + l];
        const uint_t* pw = reinterpret_cast<const uint_t*>(&v0);
        #pragma unroll
        for (int h = 0; h < 4; ++h) {
            f32x2 plo = __builtin_amdgcn_cvt_pk_f32_fp8((int)pw[h], false);
            f32x2 phi = __builtin_amdgcn_cvt_pk_f32_fp8((int)pw[h], true);
            ac[h * 4 + 0] += plo[0]; ac[h * 4 + 1] += plo[1];
            ac[h * 4 + 2] += phi[0]; ac[h * 4 + 3] += phi[1];
        }
    }
    float inv = 1.0f / fmaxf((float)c, 1.0f);
    uint_t ow[8];
    #pragma unroll
    for (int i = 0; i < 8; ++i)
        ow[i] = (uint_t)f2bf(ac[2 * i] * inv) | ((uint_t)f2bf(ac[2 * i + 1] * inv) << 16);
    uint4* dst = reinterpret_cast<uint4*>(out + (size_t)node * 256 + l * 16);
    uint4 o0 = {ow[0], ow[1], ow[2], ow[3]};
    uint4 o1 = {ow[4], ow[5], ow[6], ow[7]};
    dst[0] = o0;
    dst[1] = o1;
}

// ---------------- layer-2 mean aggregation: 8 lanes x uint4 per bf16 row, ILP-8 --------
__global__ __launch_bounds__(256) void k_agg2(
    const uint4* __restrict__ tu, const uint4* __restrict__ tp,
    const int* __restrict__ off, const int* __restrict__ cnt,
    const int* __restrict__ src_p, const int* __restrict__ src_u,
    float* __restrict__ ou, float* __restrict__ op) {
    int side = blockIdx.y;
    const uint4* T = side ? tp : tu;
    const int* of = off + side * Nn;
    const int* cn = cnt + side * Nn;
    const int* sr = side ? src_u : src_p;
    float* out = side ? op : ou;

    int node = blockIdx.x * 32 + (threadIdx.x >> 3);
    if (node >= Nn) return;
    int l = threadIdx.x & 7;
    int s = of[node], c = cn[node];
    float ac[8];
    #pragma unroll
    for (int i = 0; i < 8; ++i) ac[i] = 0.f;

    int j = 0;
    for (; j + 8 <= c; j += 8) {
        int ss[8];
        #pragma unroll
        for (int q = 0; q < 8; ++q) ss[q] = sr[s + j + q];
        uint4 vv[8];
        #pragma unroll
        for (int q = 0; q < 8; ++q) vv[q] = T[(size_t)ss[q] * 8 + l];
        #pragma unroll
        for (int q = 0; q < 8; ++q) {
            const uint_t* pw = reinterpret_cast<const uint_t*>(&vv[q]);
            #pragma unroll
            for (int h = 0; h < 4; ++h) {
                ac[h * 2 + 0] += bflo(pw[h]);
                ac[h * 2 + 1] += bfhi(pw[h]);
            }
        }
    }
    for (; j < c; ++j) {
        uint4 v0 = T[(size_t)sr[s + j] * 8 + l];
        const uint_t* pw = reinterpret_cast<const uint_t*>(&v0);
        #pragma unroll
        for (int h = 0; h < 4; ++h) {
            ac[h * 2 + 0] += bflo(pw[h]);
            ac[h * 2 + 1] += bfhi(pw[h]);
        }
    }
    float inv = 1.0f / fmaxf((float)c, 1.0f);
    float4* po = reinterpret_cast<float4*>(out + (size_t)node * 64) + l * 2;
    float4 p0 = po[0], p1 = po[1];
    p0.x += ac[0] * inv; p0.y += ac[1] * inv; p0.z += ac[2] * inv; p0.w += ac[3] * inv;
    p1.x += ac[4] * inv; p1.y += ac[5] * inv; p1.z += ac[6] * inv; p1.w += ac[7] * inv;
    po[0] = p0; po[1] = p1;
}

// ---------------- A-tile stage: 32 rows x 256 K bf16 = 16 KB, XOR-swizzled ----------------
#define STAGE_A32(Ag, mt, b)                                                        \
    {                                                                               \
        int base_ = (mt) * 32;                                                      \
        _Pragma("unroll")                                                           \
        for (int ii = 0; ii < 2; ++ii) {                                            \
            int s_ = ii * 512 + tid;                                                \
            int row_ = s_ >> 5, ks_ = s_ & 31;                                      \
            int ksl_ = ks_ ^ (row_ & 7);                                            \
            int gr_ = base_ + row_; if (gr_ >= Nn) gr_ = Nn - 1;                    \
            GLOAD((Ag) + (size_t)gr_ * 256 + ksl_ * 8, &sA[b][(s_ - lane) * 8]);    \
        }                                                                           \
    }

// ================= fused layer-1 + layer-2 GEMM, BM=32, depth-2, RAW BARRIERS ==========
// __syncthreads would emit s_waitcnt vmcnt(0) before s_barrier, draining the pipeline;
// raw s_barrier + counted vmcnt keeps stage t+1/t+2 and all epilogue stores in flight.
// vmcnt FIFO accounting (stores count!): per iter issue order = [stage t+2 (top),
// stores t (bottom)]. Wait-to constants derived by simulation: t=0->4, t=1->12,
// t>=2 (staging)->20, t==NT-2->18, t==NT-1->16. NT>=6 for GXF=256 so cases are disjoint.
// Masked stores (rows>=Nn) occur only in the globally-last tile, after all waits.
__global__ __launch_bounds__(512, 4) void k_mmf(
    const us_t* __restrict__ cu, const us_t* __restrict__ cp,
    const us_t* __restrict__ wc10, const us_t* __restrict__ wc11,
    const us_t* __restrict__ wc20, const us_t* __restrict__ wc21,
    const float* __restrict__ bu1, const float* __restrict__ bp1,
    const float* __restrict__ bu2, const float* __restrict__ bp2,
    us_t* __restrict__ tu, us_t* __restrict__ tp,
    float* __restrict__ ou, float* __restrict__ op) {
    __shared__ us_t sA[3][32 * 256];
    __shared__ us_t sH[32 * SHP];
    int tid = threadIdx.x, lane = tid & 63;
    int wc = tid >> 6;            // wave id 0..7 = N-slot
    int job = blockIdx.y;
    const us_t* Ag = job ? cp : cu;
    const us_t* W1 = job ? wc11 : wc10;
    const us_t* W2 = job ? wc21 : wc20;
    const float* b1 = job ? bp1 : bu1;
    const float* b2 = job ? bu2 : bp2;
    us_t* T = job ? tp : tu;
    float* O = job ? ou : op;

    short8 wf1[2][8];
    #pragma unroll
    for (int n = 0; n < 2; ++n)
        #pragma unroll
        for (int ks = 0; ks < 8; ++ks) {
            int col = wc * 32 + n * 16 + (lane & 15);
            wf1[n][ks] = *reinterpret_cast<const short8*>(
                W1 + (size_t)col * 256 + ks * 32 + (lane >> 4) * 8);
        }
    float bv1[2];
    #pragma unroll
    for (int n = 0; n < 2; ++n) bv1[n] = b1[wc * 32 + n * 16 + (lane & 15)];

    short8 wf2[8];
    #pragma unroll
    for (int ks = 0; ks < 8; ++ks) {
        int col = wc * 16 + (lane & 15);
        wf2[ks] = *reinterpret_cast<const short8*>(
            W2 + (size_t)col * 256 + ks * 32 + (lane >> 4) * 8);
    }
    int col2 = wc * 16 + (lane & 15);
    float bv2 = (col2 >= 64) ? b2[col2 - 64] : 0.f;
    bool top2 = col2 < 64;
    int cc2 = top2 ? col2 : col2 - 64;

    int bx = blockIdx.x;
    int NT = (MT32 - 1 - bx) / GXF + 1;     // always >= 6
    STAGE_A32(Ag, bx, 0);
    STAGE_A32(Ag, bx + GXF, 1);
    for (int t = 0; t < NT; ++t) {
        int mt = bx + t * GXF;
        if (t + 2 < NT) {
            STAGE_A32(Ag, bx + (t + 2) * GXF, (t + 2) % 3);
            if (t == 0)      { asm volatile("s_waitcnt vmcnt(4)" ::: "memory"); }
            else if (t == 1) { asm volatile("s_waitcnt vmcnt(12)" ::: "memory"); }
            else             { asm volatile("s_waitcnt vmcnt(20)" ::: "memory"); }
        } else if (t + 1 < NT) {            // t == NT-2
            asm volatile("s_waitcnt vmcnt(18)" ::: "memory");
        } else {                            // t == NT-1
            asm volatile("s_waitcnt vmcnt(16)" ::: "memory");
        }
        __builtin_amdgcn_s_barrier();
        asm volatile("" ::: "memory");      // keep LDS reads below the barrier
        const us_t* sAc = sA[t % 3];

        // ---- layer-1 MFMAs: 32x32 per wave ----
        f32x4 acc1[2][2];
        #pragma unroll
        for (int m = 0; m < 2; ++m)
            #pragma unroll
            for (int n = 0; n < 2; ++n)
                #pragma unroll
                for (int i = 0; i < 4; ++i) acc1[m][n][i] = 0.f;

        #pragma unroll
        for (int ks = 0; ks < 8; ++ks) {
            short8 af[2];
            #pragma unroll
            for (int m = 0; m < 2; ++m) {
                int row = m * 16 + (lane & 15);
                int sl = (ks * 4 + (lane >> 4)) ^ (row & 7);
                af[m] = *reinterpret_cast<const short8*>(&sAc[row * 256 + sl * 8]);
            }
            #pragma unroll
            for (int m = 0; m < 2; ++m)
                #pragma unroll
                for (int n = 0; n < 2; ++n)
                    acc1[m][n] = __builtin_amdgcn_mfma_f32_16x16x32_bf16(
                        af[m], wf1[n][ks], acc1[m][n], 0, 0, 0);
        }

        // ---- h tile -> LDS (bf16, relu+bias) ----
        #pragma unroll
        for (int n = 0; n < 2; ++n) {
            int col = wc * 32 + n * 16 + (lane & 15);
            #pragma unroll
            for (int m = 0; m < 2; ++m) {
                int r0 = m * 16 + ((lane >> 4) << 2);
                #pragma unroll
                for (int j = 0; j < 4; ++j)
                    sH[(r0 + j) * SHP + col] =
                        f2bf(fmaxf(acc1[m][n][j] + bv1[n], 0.f));
            }
        }
        asm volatile("s_waitcnt lgkmcnt(0)" ::: "memory");   // sH writes visible
        __builtin_amdgcn_s_barrier();
        asm volatile("" ::: "memory");

        // ---- layer-2 MFMAs: 32x16 per wave ----
        f32x4 acc2[2];
        #pragma unroll
        for (int m = 0; m < 2; ++m)
            #pragma unroll
            for (int i = 0; i < 4; ++i) acc2[m][i] = 0.f;

        #pragma unroll
        for (int ks = 0; ks < 8; ++ks) {
            short8 af2[2];
            #pragma unroll
            for (int m = 0; m < 2; ++m) {
                int row = m * 16 + (lane & 15);
                af2[m] = *reinterpret_cast<const short8*>(
                    &sH[row * SHP + ks * 32 + (lane >> 4) * 8]);
            }
            #pragma unroll
            for (int m = 0; m < 2; ++m)
                acc2[m] = __builtin_amdgcn_mfma_f32_16x16x32_bf16(
                    af2[m], wf2[ks], acc2[m], 0, 0, 0);
        }

        int mbase = mt * 32;
        #pragma unroll
        for (int m = 0; m < 2; ++m) {
            int row0 = mbase + m * 16 + ((lane >> 4) << 2);
            #pragma unroll
            for (int j = 0; j < 4; ++j) {
                int row = row0 + j;
                if (row >= Nn) continue;
                float v = acc2[m][j] + bv2;
                if (top2) T[(size_t)row * 64 + cc2] = f2bf(v);
                else      O[(size_t)row * 64 + cc2] = v;
            }
        }
        // next iteration's top barrier separates sH reads from the next writes
    }
}

// ---------------- launch ----------------
extern "C" void kernel_launch(void* const* d_in, const int* in_sizes, int n_in,
                              void* d_out, int out_size, void* d_ws, size_t ws_size,
                              hipStream_t stream) {
    const float* x_user    = (const float*)d_in[0];
    const float* x_product = (const float*)d_in[1];
    const int*   ei        = (const int*)d_in[2];
    const float* w_u1_l = (const float*)d_in[3];
    const float* b_u1   = (const float*)d_in[4];
    const float* w_u1_r = (const float*)d_in[5];
    const float* w_p1_l = (const float*)d_in[6];
    const float* b_p1   = (const float*)d_in[7];
    const float* w_p1_r = (const float*)d_in[8];
    const float* w_u2_l = (const float*)d_in[9];
    const float* b_u2   = (const float*)d_in[10];
    const float* w_u2_r = (const float*)d_in[11];
    const float* w_p2_l = (const float*)d_in[12];
    const float* b_p2   = (const float*)d_in[13];
    const float* w_p2_r = (const float*)d_in[14];

    float* out_u = (float*)d_out;
    float* out_p = out_u + (size_t)Nn * CLSS;

    char* w = (char*)d_ws;
    int* bin_cnt  = (int*)w; w += (size_t)2 * NBIN * 4;
    int* off  = (int*)w;  w += (size_t)2 * Nn * 4;
    int* cnt  = (int*)w;  w += (size_t)2 * Nn * 4;
    int* src_p = (int*)w; w += (size_t)Ee * 4;
    int* src_u = (int*)w; w += (size_t)Ee * 4;
    uint_t* ent_p = (uint_t*)w; w += (size_t)NBIN * BCAP * 4;
    uint_t* ent_u = (uint_t*)w; w += (size_t)NBIN * BCAP * 4;
    uintptr_t a = (uintptr_t)w; a = (a + 255) & ~(uintptr_t)255; w = (char*)a;
    us_t* cu   = (us_t*)w; w += (size_t)Nn * 256 * 2;   // [mean_u | x_prod]
    us_t* cp   = (us_t*)w; w += (size_t)Nn * 256 * 2;   // [mean_p | x_user]
    uint_t* xf8u = (uint_t*)w; w += (size_t)Nn * FIN;
    uint_t* xf8p = (uint_t*)w; w += (size_t)Nn * FIN;
    us_t* tbuf_u = (us_t*)w; w += (size_t)Nn * CLSS * 2;
    us_t* tbuf_p = (us_t*)w; w += (size_t)Nn * CLSS * 2;
    us_t* wc10 = (us_t*)w; w += (size_t)256 * 256 * 2;
    us_t* wc11 = (us_t*)w; w += (size_t)256 * 256 * 2;
    us_t* wc20 = (us_t*)w; w += (size_t)128 * 256 * 2;
    us_t* wc21 = (us_t*)w; w += (size_t)128 * 256 * 2;

    // ---- front-end: zero bin counters, then bin || cvtw || cvtx in one launch ----
    hipMemsetAsync(bin_cnt, 0, (size_t)2 * NBIN * 4, stream);
    k_front<<<NEB + 96 + 512, 512, 0, stream>>>(
        ei, x_user, x_product,
        w_u1_l, w_u1_r, w_p1_l, w_p1_r, w_u2_l, w_u2_r, w_p2_l, w_p2_r,
        cu, cp, xf8u, xf8p, wc10, wc11, wc20, wc21,
        bin_cnt, ent_p, ent_u);
    dim3 gsc(NBIN, 2);
    k_scatter<<<gsc, 512, 0, stream>>>(ent_p, ent_u, bin_cnt,
                                       off, cnt, src_p, src_u);

    // ---- layer 1 aggregation ----
    dim3 ga1((Nn + 31) / 32, 2);
    k_agg1<<<ga1, 256, 0, stream>>>((const uint4*)xf8u, (const uint4*)xf8p,
                                    off, cnt, src_p, src_u, cu, cp);

    // ---- fused layer-1 + layer-2 GEMM ----
    dim3 g1(GXF, 2);
    k_mmf<<<g1, 512, 0, stream>>>(cu, cp, wc10, wc11, wc20, wc21,
                                  b_u1, b_p1, b_u2, b_p2,
                                  tbuf_u, tbuf_p, out_u, out_p);

    // ---- layer 2 aggregation ----
    dim3 ga2((Nn + 31) / 32, 2);
    k_agg2<<<ga2, 256, 0, stream>>>((const uint4*)tbuf_u, (const uint4*)tbuf_p,
                                    off, cnt, src_p, src_u, out_u, out_p);
}